// Round 4
// baseline (658.176 us; speedup 1.0000x reference)
//
#include <hip/hip_runtime.h>

#define NUSERS 100000
#define NITEMS 50000
#define NTOT   150000
#define NEDGE  1000000

// ---- init: emb = concat(user, item); out = emb (embeds_lst[0]) ----
__global__ void k_init(const float* __restrict__ ue, const float* __restrict__ ie,
                       float* __restrict__ emb, float* __restrict__ out) {
  int i = blockIdx.x * 256 + threadIdx.x;  // float4 index
  if (i >= NTOT * 16) return;
  float4 v = (i < NUSERS * 16) ? ((const float4*)ue)[i]
                               : ((const float4*)ie)[i - NUSERS * 16];
  ((float4*)emb)[i] = v;
  ((float4*)out)[i] = v;
}

// ---- CSR build: histogram -> scan -> fill ----
__global__ void k_hist(const int* __restrict__ rows, int* __restrict__ cnt) {
  int e = blockIdx.x * 256 + threadIdx.x;
  if (e < NEDGE) atomicAdd(&cnt[rows[e]], 1);
}

__global__ void k_scan1(const int* __restrict__ cnt, int* __restrict__ partial,
                        int* __restrict__ blocksums) {
  __shared__ int s[256];
  int t = threadIdx.x, b = blockIdx.x;
  int base = b * 2048 + t * 8;
  int pre[8]; int sum = 0;
  #pragma unroll
  for (int j = 0; j < 8; ++j) {
    int idx = base + j;
    int x = (idx < NTOT) ? cnt[idx] : 0;
    pre[j] = sum; sum += x;
  }
  s[t] = sum; __syncthreads();
  for (int off = 1; off < 256; off <<= 1) {
    int x = (t >= off) ? s[t - off] : 0;
    __syncthreads(); s[t] += x; __syncthreads();
  }
  int excl = s[t] - sum;
  #pragma unroll
  for (int j = 0; j < 8; ++j) {
    int idx = base + j;
    if (idx < NTOT) partial[idx] = excl + pre[j];
  }
  if (t == 255) blocksums[b] = s[255];
}

__global__ void k_scan2(const int* __restrict__ blocksums, int* __restrict__ blockoffs, int nblk) {
  __shared__ int s[128];
  int t = threadIdx.x;
  int x = (t < nblk) ? blocksums[t] : 0;
  s[t] = x; __syncthreads();
  for (int off = 1; off < 128; off <<= 1) {
    int y = (t >= off) ? s[t - off] : 0;
    __syncthreads(); s[t] += y; __syncthreads();
  }
  if (t < nblk) blockoffs[t] = s[t] - x;
}

__global__ void k_scan3(int* __restrict__ row_ptr, const int* __restrict__ blockoffs,
                        int* __restrict__ cursor) {
  int i = blockIdx.x * 256 + threadIdx.x;
  if (i < NTOT) {
    int v = row_ptr[i] + blockoffs[i >> 11];
    row_ptr[i] = v; cursor[i] = v;
  }
  if (i == 0) row_ptr[NTOT] = NEDGE;
}

__global__ void k_fill(const int* __restrict__ rows, const int* __restrict__ cols,
                       const float* __restrict__ vals, int* __restrict__ cursor,
                       int* __restrict__ ecols, float* __restrict__ evals) {
  int e = blockIdx.x * 256 + threadIdx.x;
  if (e >= NEDGE) return;
  int r = rows[e];
  int pos = atomicAdd(&cursor[r], 1);
  ecols[pos] = cols[e];
  evals[pos] = vals[e];
}

// ---- QKV projection: shuffle-free, LDS-staged emb tile ----
// Block = 256 threads = 4 waves; block handles 64 nodes (16 per wave).
#define ESTRIDE 68
__global__ void __launch_bounds__(256) k_qkv(const float* __restrict__ emb,
    const float* __restrict__ Wq, const float* __restrict__ Wk, const float* __restrict__ Wv,
    float* __restrict__ Q, float* __restrict__ KV) {
  __shared__ float wq[4096], wk[4096], wv[4096];
  __shared__ float es[64 * ESTRIDE];
  int t = threadIdx.x;
  for (int i = t; i < 4096; i += 256) { wq[i] = Wq[i]; wk[i] = Wk[i]; wv[i] = Wv[i]; }
  int n0 = blockIdx.x * 64;
  {
    int i = t >> 4, c = t & 15;  // node-row, float4 chunk
    #pragma unroll
    for (int r = 0; r < 4; ++r) {
      int li = i + r * 16;
      int node = n0 + li;
      float4 v = make_float4(0.f, 0.f, 0.f, 0.f);
      if (node < NTOT) v = ((const float4*)emb)[node * 16 + c];
      *(float4*)&es[li * ESTRIDE + c * 4] = v;
    }
  }
  __syncthreads();
  int wave = t >> 6, lane = t & 63;
  float qa[16], ka[16], va[16];
  #pragma unroll
  for (int u = 0; u < 16; ++u) { qa[u] = 0.f; ka[u] = 0.f; va[u] = 0.f; }
  const float* eb = &es[(wave * 16) * ESTRIDE];
  for (int k0 = 0; k0 < 64; k0 += 4) {
    float q0 = wq[(k0 + 0) * 64 + lane], q1 = wq[(k0 + 1) * 64 + lane];
    float q2 = wq[(k0 + 2) * 64 + lane], q3 = wq[(k0 + 3) * 64 + lane];
    float k0w = wk[(k0 + 0) * 64 + lane], k1w = wk[(k0 + 1) * 64 + lane];
    float k2w = wk[(k0 + 2) * 64 + lane], k3w = wk[(k0 + 3) * 64 + lane];
    float v0 = wv[(k0 + 0) * 64 + lane], v1 = wv[(k0 + 1) * 64 + lane];
    float v2 = wv[(k0 + 2) * 64 + lane], v3 = wv[(k0 + 3) * 64 + lane];
    #pragma unroll
    for (int u = 0; u < 16; ++u) {
      float4 e4 = *(const float4*)&eb[u * ESTRIDE + k0];  // broadcast
      qa[u] = fmaf(e4.x, q0, qa[u]);
      qa[u] = fmaf(e4.y, q1, qa[u]);
      qa[u] = fmaf(e4.z, q2, qa[u]);
      qa[u] = fmaf(e4.w, q3, qa[u]);
      ka[u] = fmaf(e4.x, k0w, ka[u]);
      ka[u] = fmaf(e4.y, k1w, ka[u]);
      ka[u] = fmaf(e4.z, k2w, ka[u]);
      ka[u] = fmaf(e4.w, k3w, ka[u]);
      va[u] = fmaf(e4.x, v0, va[u]);
      va[u] = fmaf(e4.y, v1, va[u]);
      va[u] = fmaf(e4.z, v2, va[u]);
      va[u] = fmaf(e4.w, v3, va[u]);
    }
  }
  #pragma unroll
  for (int u = 0; u < 16; ++u) {
    int n = n0 + wave * 16 + u;
    if (n < NTOT) {
      Q[n * 64 + lane] = qa[u];
      KV[n * 128 + lane] = ka[u];
      KV[n * 128 + 64 + lane] = va[u];
    }
  }
}

// ---- GT layer v3: wave = node; 4 edge-slots x 16 lanes x float4 ----
// es = lane>>4 (edge slot), dl = lane&15 (dims 4*dl..4*dl+3), head = dl>>2.
__global__ void __launch_bounds__(256) k_gt(const float* __restrict__ Q,
    const float* __restrict__ KV, const int* __restrict__ row_ptr,
    const int* __restrict__ ecols, float* __restrict__ emb_out, float* __restrict__ acc_out) {
  int t = threadIdx.x;
  int n = blockIdx.x * 4 + (t >> 6);
  if (n >= NTOT) return;
  int lane = t & 63;
  int es = lane >> 4;
  int dl = lane & 15;
  float4 q4 = *(const float4*)&Q[n * 64 + dl * 4];
  int s     = __builtin_amdgcn_readfirstlane(row_ptr[n]);
  int e_end = __builtin_amdgcn_readfirstlane(row_ptr[n + 1]);
  float den = 0.f;
  float4 acc = make_float4(0.f, 0.f, 0.f, 0.f);
  #pragma unroll 2
  for (int p = s; p < e_end; p += 4) {
    int idx = p + es;
    float ex = 0.f;
    float4 v4 = make_float4(0.f, 0.f, 0.f, 0.f);
    if (idx < e_end) {
      int c = ecols[idx];
      const float* kb = KV + c * 128 + dl * 4;
      float4 k4 = *(const float4*)kb;
      v4 = *(const float4*)(kb + 64);
      float x = q4.x * k4.x + q4.y * k4.y + q4.z * k4.z + q4.w * k4.w;
      // head sum: dims of head h live in lanes with dl in {4h..4h+3} (same es)
      x += __shfl_xor(x, 1);
      x += __shfl_xor(x, 2);
      x = fminf(fmaxf(x, -10.f), 10.f);
      ex = __expf(x);
    }
    den += ex;
    acc.x = fmaf(ex, v4.x, acc.x);
    acc.y = fmaf(ex, v4.y, acc.y);
    acc.z = fmaf(ex, v4.z, acc.z);
    acc.w = fmaf(ex, v4.w, acc.w);
  }
  // reduce across the 4 edge slots
  #pragma unroll
  for (int off = 16; off <= 32; off <<= 1) {
    den  += __shfl_xor(den, off);
    acc.x += __shfl_xor(acc.x, off);
    acc.y += __shfl_xor(acc.y, off);
    acc.z += __shfl_xor(acc.z, off);
    acc.w += __shfl_xor(acc.w, off);
  }
  float inv = 1.f / (den + 1e-8f);
  float4 r = make_float4(acc.x * inv, acc.y * inv, acc.z * inv, acc.w * inv);
  if (es == 0) {
    *(float4*)&emb_out[n * 64 + dl * 4] = r;
  } else if (es == 1) {
    float4 o = *(const float4*)&acc_out[n * 64 + dl * 4];
    o.x += r.x; o.y += r.y; o.z += r.z; o.w += r.w;
    *(float4*)&acc_out[n * 64 + dl * 4] = o;
  }
}

// ---- GCN layer v3 (spmm): same 4-slot x float4 structure ----
__global__ void __launch_bounds__(256) k_gcn(const float* __restrict__ emb,
    const int* __restrict__ row_ptr, const int* __restrict__ ecols, const float* __restrict__ evals,
    float* __restrict__ emb_out, float* __restrict__ acc_out) {
  int t = threadIdx.x;
  int n = blockIdx.x * 4 + (t >> 6);
  if (n >= NTOT) return;
  int lane = t & 63;
  int es = lane >> 4;
  int dl = lane & 15;
  int s     = __builtin_amdgcn_readfirstlane(row_ptr[n]);
  int e_end = __builtin_amdgcn_readfirstlane(row_ptr[n + 1]);
  float4 a = make_float4(0.f, 0.f, 0.f, 0.f);
  #pragma unroll 2
  for (int p = s; p < e_end; p += 4) {
    int idx = p + es;
    if (idx < e_end) {
      int c = ecols[idx];
      float w = evals[idx];
      float4 e4 = *(const float4*)&emb[c * 64 + dl * 4];
      a.x = fmaf(w, e4.x, a.x);
      a.y = fmaf(w, e4.y, a.y);
      a.z = fmaf(w, e4.z, a.z);
      a.w = fmaf(w, e4.w, a.w);
    }
  }
  #pragma unroll
  for (int off = 16; off <= 32; off <<= 1) {
    a.x += __shfl_xor(a.x, off);
    a.y += __shfl_xor(a.y, off);
    a.z += __shfl_xor(a.z, off);
    a.w += __shfl_xor(a.w, off);
  }
  if (es == 0) {
    *(float4*)&emb_out[n * 64 + dl * 4] = a;
  } else if (es == 1) {
    float4 o = *(const float4*)&acc_out[n * 64 + dl * 4];
    o.x += a.x; o.y += a.y; o.z += a.z; o.w += a.w;
    *(float4*)&acc_out[n * 64 + dl * 4] = o;
  }
}

extern "C" void kernel_launch(void* const* d_in, const int* in_sizes, int n_in,
                              void* d_out, int out_size, void* d_ws, size_t ws_size,
                              hipStream_t stream) {
  const int*   rows = (const int*)d_in[0];
  const int*   cols = (const int*)d_in[1];
  const float* vals = (const float*)d_in[2];
  const float* ue   = (const float*)d_in[3];
  const float* ie   = (const float*)d_in[4];
  const float* Wq   = (const float*)d_in[5];
  const float* Wk   = (const float*)d_in[6];
  const float* Wv   = (const float*)d_in[7];
  float* out = (float*)d_out;

  char* p = (char*)d_ws;
  auto alloc = [&](size_t b) { char* r = p; p += (b + 255) & ~(size_t)255; return (void*)r; };
  int*   cnt     = (int*)alloc((size_t)NTOT * 4);
  int*   row_ptr = (int*)alloc((size_t)(NTOT + 1) * 4);
  int*   cursor  = (int*)alloc((size_t)NTOT * 4);
  int*   bsums   = (int*)alloc(128 * 4);
  int*   boffs   = (int*)alloc(128 * 4);
  int*   ecols   = (int*)alloc((size_t)NEDGE * 4);
  float* evals   = (float*)alloc((size_t)NEDGE * 4);
  float* Q    = (float*)alloc((size_t)NTOT * 64 * 4);
  float* KV   = (float*)alloc((size_t)NTOT * 128 * 4);
  float* embA = (float*)alloc((size_t)NTOT * 64 * 4);
  float* embB = (float*)alloc((size_t)NTOT * 64 * 4);

  hipMemsetAsync(cnt, 0, (size_t)NTOT * 4, stream);
  k_hist<<<(NEDGE + 255) / 256, 256, 0, stream>>>(rows, cnt);
  int nblk = (NTOT + 2047) / 2048;  // 74
  k_scan1<<<nblk, 256, 0, stream>>>(cnt, row_ptr, bsums);
  k_scan2<<<1, 128, 0, stream>>>(bsums, boffs, nblk);
  k_scan3<<<(NTOT + 255) / 256, 256, 0, stream>>>(row_ptr, boffs, cursor);
  k_fill<<<(NEDGE + 255) / 256, 256, 0, stream>>>(rows, cols, vals, cursor, ecols, evals);
  k_init<<<(NTOT * 16 + 255) / 256, 256, 0, stream>>>(ue, ie, embA, out);

  float* cur = embA;
  float* nxt = embB;
  for (int l = 0; l < 2; ++l) {
    k_qkv<<<(NTOT + 63) / 64, 256, 0, stream>>>(cur, Wq + l * 4096, Wk + l * 4096, Wv + l * 4096,
                                                Q, KV);
    k_gt<<<(NTOT + 3) / 4, 256, 0, stream>>>(Q, KV, row_ptr, ecols, nxt, out);
    float* tmp = cur; cur = nxt; nxt = tmp;
  }
  for (int l = 0; l < 2; ++l) {
    k_gcn<<<(NTOT + 3) / 4, 256, 0, stream>>>(cur, row_ptr, ecols, evals, nxt, out);
    float* tmp = cur; cur = nxt; nxt = tmp;
  }
}

// Round 5
// 622.258 us; speedup vs baseline: 1.0577x; 1.0577x over previous
//
#include <hip/hip_runtime.h>

#define NUSERS 100000
#define NITEMS 50000
#define NTOT   150000
#define NEDGE  1000000

typedef unsigned int uint32;

__device__ __forceinline__ unsigned short f2bf(float f) {
  unsigned int u = __float_as_uint(f);
  u += 0x7FFFu + ((u >> 16) & 1u);   // round-to-nearest-even
  return (unsigned short)(u >> 16);
}

// ---- init: emb = concat(user, item); out = emb (embeds_lst[0]) ----
__global__ void k_init(const float* __restrict__ ue, const float* __restrict__ ie,
                       float* __restrict__ emb, float* __restrict__ out) {
  int i = blockIdx.x * 256 + threadIdx.x;  // float4 index
  if (i >= NTOT * 16) return;
  float4 v = (i < NUSERS * 16) ? ((const float4*)ue)[i]
                               : ((const float4*)ie)[i - NUSERS * 16];
  ((float4*)emb)[i] = v;
  ((float4*)out)[i] = v;
}

// ---- CSR build: histogram -> scan -> fill ----
__global__ void k_hist(const int* __restrict__ rows, int* __restrict__ cnt) {
  int e = blockIdx.x * 256 + threadIdx.x;
  if (e < NEDGE) atomicAdd(&cnt[rows[e]], 1);
}

__global__ void k_scan1(const int* __restrict__ cnt, int* __restrict__ partial,
                        int* __restrict__ blocksums) {
  __shared__ int s[256];
  int t = threadIdx.x, b = blockIdx.x;
  int base = b * 2048 + t * 8;
  int pre[8]; int sum = 0;
  #pragma unroll
  for (int j = 0; j < 8; ++j) {
    int idx = base + j;
    int x = (idx < NTOT) ? cnt[idx] : 0;
    pre[j] = sum; sum += x;
  }
  s[t] = sum; __syncthreads();
  for (int off = 1; off < 256; off <<= 1) {
    int x = (t >= off) ? s[t - off] : 0;
    __syncthreads(); s[t] += x; __syncthreads();
  }
  int excl = s[t] - sum;
  #pragma unroll
  for (int j = 0; j < 8; ++j) {
    int idx = base + j;
    if (idx < NTOT) partial[idx] = excl + pre[j];
  }
  if (t == 255) blocksums[b] = s[255];
}

__global__ void k_scan2(const int* __restrict__ blocksums, int* __restrict__ blockoffs, int nblk) {
  __shared__ int s[128];
  int t = threadIdx.x;
  int x = (t < nblk) ? blocksums[t] : 0;
  s[t] = x; __syncthreads();
  for (int off = 1; off < 128; off <<= 1) {
    int y = (t >= off) ? s[t - off] : 0;
    __syncthreads(); s[t] += y; __syncthreads();
  }
  if (t < nblk) blockoffs[t] = s[t] - x;
}

__global__ void k_scan3(int* __restrict__ row_ptr, const int* __restrict__ blockoffs,
                        int* __restrict__ cursor) {
  int i = blockIdx.x * 256 + threadIdx.x;
  if (i < NTOT) {
    int v = row_ptr[i] + blockoffs[i >> 11];
    row_ptr[i] = v; cursor[i] = v;
  }
  if (i == 0) row_ptr[NTOT] = NEDGE;
}

__global__ void k_fill(const int* __restrict__ rows, const int* __restrict__ cols,
                       const float* __restrict__ vals, int* __restrict__ cursor,
                       int* __restrict__ ecols, float* __restrict__ evals) {
  int e = blockIdx.x * 256 + threadIdx.x;
  if (e >= NEDGE) return;
  int r = rows[e];
  int pos = atomicAdd(&cursor[r], 1);
  ecols[pos] = cols[e];
  evals[pos] = vals[e];
}

// ---- QKV projection: shuffle-free, LDS-staged emb tile ----
// Block = 256 threads = 4 waves; block handles 64 nodes (16 per wave).
// Q kept fp32 (dense per-node read in k_gt). K/V packed bf16 into KVb:
// per node 64 uints; chunk c (4 dims): uints [c*4+0]=k(4c,4c+1), [c*4+1]=k(4c+2,4c+3),
// [c*4+2]=v(4c,4c+1), [c*4+3]=v(4c+2,4c+3).
// Lanes 0-31 own K dim-pairs (2m,2m+1); lanes 32-63 own V dim-pairs. Q: lane=dim.
#define ESTRIDE 68
__global__ void __launch_bounds__(256) k_qkv(const float* __restrict__ emb,
    const float* __restrict__ Wq, const float* __restrict__ Wk, const float* __restrict__ Wv,
    float* __restrict__ Q, uint32* __restrict__ KVb) {
  __shared__ float wq[4096], wk[4096], wv[4096];
  __shared__ float es[64 * ESTRIDE];
  int t = threadIdx.x;
  for (int i = t; i < 4096; i += 256) { wq[i] = Wq[i]; wk[i] = Wk[i]; wv[i] = Wv[i]; }
  int n0 = blockIdx.x * 64;
  {
    int i = t >> 4, c = t & 15;  // node-row, float4 chunk
    #pragma unroll
    for (int r = 0; r < 4; ++r) {
      int li = i + r * 16;
      int node = n0 + li;
      float4 v = make_float4(0.f, 0.f, 0.f, 0.f);
      if (node < NTOT) v = ((const float4*)emb)[node * 16 + c];
      *(float4*)&es[li * ESTRIDE + c * 4] = v;
    }
  }
  __syncthreads();
  int wave = t >> 6, lane = t & 63;
  int half = lane >> 5;            // 0 -> K, 1 -> V
  int m = lane & 31;               // dim pair (2m, 2m+1)
  const float* wkv = half ? wv : wk;
  float qa[16], kv0[16], kv1[16];
  #pragma unroll
  for (int u = 0; u < 16; ++u) { qa[u] = 0.f; kv0[u] = 0.f; kv1[u] = 0.f; }
  const float* eb = &es[(wave * 16) * ESTRIDE];
  for (int k0 = 0; k0 < 64; k0 += 4) {
    float q0 = wq[(k0 + 0) * 64 + lane], q1 = wq[(k0 + 1) * 64 + lane];
    float q2 = wq[(k0 + 2) * 64 + lane], q3 = wq[(k0 + 3) * 64 + lane];
    float2 w0 = *(const float2*)&wkv[(k0 + 0) * 64 + 2 * m];
    float2 w1 = *(const float2*)&wkv[(k0 + 1) * 64 + 2 * m];
    float2 w2 = *(const float2*)&wkv[(k0 + 2) * 64 + 2 * m];
    float2 w3 = *(const float2*)&wkv[(k0 + 3) * 64 + 2 * m];
    #pragma unroll
    for (int u = 0; u < 16; ++u) {
      float4 e4 = *(const float4*)&eb[u * ESTRIDE + k0];  // broadcast
      qa[u] = fmaf(e4.x, q0, qa[u]);
      qa[u] = fmaf(e4.y, q1, qa[u]);
      qa[u] = fmaf(e4.z, q2, qa[u]);
      qa[u] = fmaf(e4.w, q3, qa[u]);
      kv0[u] = fmaf(e4.x, w0.x, kv0[u]);
      kv0[u] = fmaf(e4.y, w1.x, kv0[u]);
      kv0[u] = fmaf(e4.z, w2.x, kv0[u]);
      kv0[u] = fmaf(e4.w, w3.x, kv0[u]);
      kv1[u] = fmaf(e4.x, w0.y, kv1[u]);
      kv1[u] = fmaf(e4.y, w1.y, kv1[u]);
      kv1[u] = fmaf(e4.z, w2.y, kv1[u]);
      kv1[u] = fmaf(e4.w, w3.y, kv1[u]);
    }
  }
  int uidx = (m >> 1) * 4 + half * 2 + (m & 1);
  #pragma unroll
  for (int u = 0; u < 16; ++u) {
    int n = n0 + wave * 16 + u;
    if (n < NTOT) {
      Q[n * 64 + lane] = qa[u];
      KVb[n * 64 + uidx] = (uint32)f2bf(kv0[u]) | ((uint32)f2bf(kv1[u]) << 16);
    }
  }
}

// ---- GT layer: wave = node; 4 edge-slots x 16 lanes; one dwordx4/edge ----
// es = lane>>4 (edge slot), dl = lane&15 (dims 4*dl..4*dl+3), head = dl>>2.
__global__ void __launch_bounds__(256) k_gt(const float* __restrict__ Q,
    const uint32* __restrict__ KVb, const int* __restrict__ row_ptr,
    const int* __restrict__ ecols, float* __restrict__ emb_out, float* __restrict__ acc_out) {
  int t = threadIdx.x;
  int n = blockIdx.x * 4 + (t >> 6);
  if (n >= NTOT) return;
  int lane = t & 63;
  int es = lane >> 4;
  int dl = lane & 15;
  float4 q4 = *(const float4*)&Q[n * 64 + dl * 4];
  int s     = __builtin_amdgcn_readfirstlane(row_ptr[n]);
  int e_end = __builtin_amdgcn_readfirstlane(row_ptr[n + 1]);
  float den = 0.f;
  float4 acc = make_float4(0.f, 0.f, 0.f, 0.f);
  #pragma unroll 2
  for (int p = s; p < e_end; p += 4) {
    int idx = p + es;
    float ex = 0.f;
    float4 v4 = make_float4(0.f, 0.f, 0.f, 0.f);
    if (idx < e_end) {
      int c = ecols[idx];
      uint4 w = *(const uint4*)&KVb[c * 64 + dl * 4];
      float kx = __uint_as_float(w.x << 16);
      float ky = __uint_as_float(w.x & 0xFFFF0000u);
      float kz = __uint_as_float(w.y << 16);
      float kw = __uint_as_float(w.y & 0xFFFF0000u);
      v4.x = __uint_as_float(w.z << 16);
      v4.y = __uint_as_float(w.z & 0xFFFF0000u);
      v4.z = __uint_as_float(w.w << 16);
      v4.w = __uint_as_float(w.w & 0xFFFF0000u);
      float x = q4.x * kx + q4.y * ky + q4.z * kz + q4.w * kw;
      x += __shfl_xor(x, 1);
      x += __shfl_xor(x, 2);
      x = fminf(fmaxf(x, -10.f), 10.f);
      ex = __expf(x);
    }
    den += ex;
    acc.x = fmaf(ex, v4.x, acc.x);
    acc.y = fmaf(ex, v4.y, acc.y);
    acc.z = fmaf(ex, v4.z, acc.z);
    acc.w = fmaf(ex, v4.w, acc.w);
  }
  // reduce across the 4 edge slots
  #pragma unroll
  for (int off = 16; off <= 32; off <<= 1) {
    den  += __shfl_xor(den, off);
    acc.x += __shfl_xor(acc.x, off);
    acc.y += __shfl_xor(acc.y, off);
    acc.z += __shfl_xor(acc.z, off);
    acc.w += __shfl_xor(acc.w, off);
  }
  float inv = 1.f / (den + 1e-8f);
  float4 r = make_float4(acc.x * inv, acc.y * inv, acc.z * inv, acc.w * inv);
  if (es == 0) {
    *(float4*)&emb_out[n * 64 + dl * 4] = r;
  } else if (es == 1) {
    float4 o = *(const float4*)&acc_out[n * 64 + dl * 4];
    o.x += r.x; o.y += r.y; o.z += r.z; o.w += r.w;
    *(float4*)&acc_out[n * 64 + dl * 4] = o;
  }
}

// ---- GCN layer (spmm): R3 form — wave per node, lane = dim, 4x unrolled ----
__global__ void __launch_bounds__(256) k_gcn(const float* __restrict__ emb,
    const int* __restrict__ row_ptr, const int* __restrict__ ecols, const float* __restrict__ evals,
    float* __restrict__ emb_out, float* __restrict__ acc_out) {
  int t = threadIdx.x;
  int n = blockIdx.x * 4 + (t >> 6);
  if (n >= NTOT) return;
  int lane = t & 63;
  int s     = __builtin_amdgcn_readfirstlane(row_ptr[n]);
  int e_end = __builtin_amdgcn_readfirstlane(row_ptr[n + 1]);
  float a0 = 0.f, a1 = 0.f, a2 = 0.f, a3 = 0.f;
  int p = s;
  for (; p + 4 <= e_end; p += 4) {
    int c0 = ecols[p], c1 = ecols[p + 1], c2 = ecols[p + 2], c3 = ecols[p + 3];
    float w0 = evals[p], w1 = evals[p + 1], w2 = evals[p + 2], w3 = evals[p + 3];
    float m0 = emb[c0 * 64 + lane];
    float m1 = emb[c1 * 64 + lane];
    float m2 = emb[c2 * 64 + lane];
    float m3 = emb[c3 * 64 + lane];
    a0 = fmaf(w0, m0, a0);
    a1 = fmaf(w1, m1, a1);
    a2 = fmaf(w2, m2, a2);
    a3 = fmaf(w3, m3, a3);
  }
  for (; p < e_end; ++p) {
    int c = ecols[p];
    a0 = fmaf(evals[p], emb[c * 64 + lane], a0);
  }
  float acc = (a0 + a1) + (a2 + a3);
  emb_out[n * 64 + lane] = acc;
  acc_out[n * 64 + lane] += acc;
}

extern "C" void kernel_launch(void* const* d_in, const int* in_sizes, int n_in,
                              void* d_out, int out_size, void* d_ws, size_t ws_size,
                              hipStream_t stream) {
  const int*   rows = (const int*)d_in[0];
  const int*   cols = (const int*)d_in[1];
  const float* vals = (const float*)d_in[2];
  const float* ue   = (const float*)d_in[3];
  const float* ie   = (const float*)d_in[4];
  const float* Wq   = (const float*)d_in[5];
  const float* Wk   = (const float*)d_in[6];
  const float* Wv   = (const float*)d_in[7];
  float* out = (float*)d_out;

  char* p = (char*)d_ws;
  auto alloc = [&](size_t b) { char* r = p; p += (b + 255) & ~(size_t)255; return (void*)r; };
  int*   cnt     = (int*)alloc((size_t)NTOT * 4);
  int*   row_ptr = (int*)alloc((size_t)(NTOT + 1) * 4);
  int*   cursor  = (int*)alloc((size_t)NTOT * 4);
  int*   bsums   = (int*)alloc(128 * 4);
  int*   boffs   = (int*)alloc(128 * 4);
  int*   ecols   = (int*)alloc((size_t)NEDGE * 4);
  float* evals   = (float*)alloc((size_t)NEDGE * 4);
  float*  Q   = (float*)alloc((size_t)NTOT * 64 * 4);
  uint32* KVb = (uint32*)alloc((size_t)NTOT * 64 * 4);  // 64 uints/node = 256 B
  float* embA = (float*)alloc((size_t)NTOT * 64 * 4);
  float* embB = (float*)alloc((size_t)NTOT * 64 * 4);

  hipMemsetAsync(cnt, 0, (size_t)NTOT * 4, stream);
  k_hist<<<(NEDGE + 255) / 256, 256, 0, stream>>>(rows, cnt);
  int nblk = (NTOT + 2047) / 2048;  // 74
  k_scan1<<<nblk, 256, 0, stream>>>(cnt, row_ptr, bsums);
  k_scan2<<<1, 128, 0, stream>>>(bsums, boffs, nblk);
  k_scan3<<<(NTOT + 255) / 256, 256, 0, stream>>>(row_ptr, boffs, cursor);
  k_fill<<<(NEDGE + 255) / 256, 256, 0, stream>>>(rows, cols, vals, cursor, ecols, evals);
  k_init<<<(NTOT * 16 + 255) / 256, 256, 0, stream>>>(ue, ie, embA, out);

  float* cur = embA;
  float* nxt = embB;
  for (int l = 0; l < 2; ++l) {
    k_qkv<<<(NTOT + 63) / 64, 256, 0, stream>>>(cur, Wq + l * 4096, Wk + l * 4096, Wv + l * 4096,
                                                Q, KVb);
    k_gt<<<(NTOT + 3) / 4, 256, 0, stream>>>(Q, KVb, row_ptr, ecols, nxt, out);
    float* tmp = cur; cur = nxt; nxt = tmp;
  }
  for (int l = 0; l < 2; ++l) {
    k_gcn<<<(NTOT + 3) / 4, 256, 0, stream>>>(cur, row_ptr, ecols, evals, nxt, out);
    float* tmp = cur; cur = nxt; nxt = tmp;
  }
}